// Round 1
// baseline (737.730 us; speedup 1.0000x reference)
//
#include <hip/hip_runtime.h>

// Fused relational-attention scorer for MI355X (gfx950).
//
//   T = h.reshape(R,B,H,D); hidden = tanh(T@W1 + b1); s = hidden.w2 (+b2)
//   alpha = softmax_r(s); out[b,h,:] = sum_r alpha * T[r,b,h,:]
//
// R=4, B=65536, H=8, D=64.  Memory floor: 536MB read + 134MB write ~ 106us.
// Matmul done in bf16 MFMA (16x16x32) -> compute ~8us, kernel memory-bound.
// T kept in LDS as fp32 (XOR-swizzled rows) so the final weighted sum is
// full-precision; bf16 rounding only affects scores -> alpha (err ~1e-3).
// b2 is a constant shift across relations -> softmax-invariant -> dropped.

typedef float f32x4 __attribute__((ext_vector_type(4)));
typedef short bf16x8 __attribute__((ext_vector_type(8)));

#define RSTRIDE (65536 * 512)   // floats per relation slab of h
#define PAIRS 32                // (b,h) pairs per tile (=> 128 matmul rows)
#define TILES_PER_BLOCK 8
#define NBLOCKS 2048            // 2048 * 8 * 32 = 524288 = B*H exactly

__device__ __forceinline__ unsigned short f2bf(float f) {
  // fp32 -> bf16 round-to-nearest-even (finite inputs only)
  unsigned int u = __builtin_bit_cast(unsigned int, f);
  u += 0x7FFFu + ((u >> 16) & 1u);
  return (unsigned short)(u >> 16);
}

__device__ __forceinline__ float fast_tanh(float x) {
  // tanh(x) = 1 - 2/(exp(2x)+1); v_exp + v_rcp, ~1ulp each
  float e = __expf(2.0f * x);
  return 1.0f - 2.0f * __builtin_amdgcn_rcpf(e + 1.0f);
}

__global__ __launch_bounds__(256, 3) void fused_relattn(
    const float* __restrict__ h, const float* __restrict__ W1,
    const float* __restrict__ b1, const float* __restrict__ w2,
    float* __restrict__ out) {
  // T rows: [row = r*32 + bhl][d], fp32, XOR-swizzled 32B blocks within a row
  __shared__ float Tlds[128 * 64];   // 32 KB
  __shared__ float Sc[4 * 32];       // scores[r][bhl]

  const int tid = threadIdx.x;
  const int w = tid >> 6;     // wave id == relation r it owns
  const int lane = tid & 63;
  const int l15 = lane & 15;
  const int lhi = lane >> 4;  // 0..3

  // ---- kernel-lifetime preload: W1 B-fragments (bf16), b1/w2 per-lane ----
  // B[k][n]: n = nt*16 + (lane&15), k = kh*32 + (lane>>4)*8 + j.
  // (A and B use the same lane->k map, so any k-permutation cancels.)
  bf16x8 w1f[2][4];
#pragma unroll
  for (int kh = 0; kh < 2; ++kh) {
#pragma unroll
    for (int nt = 0; nt < 4; ++nt) {
      bf16x8 f;
#pragma unroll
      for (int j = 0; j < 8; ++j) {
        int k = kh * 32 + lhi * 8 + j;
        f[j] = (short)f2bf(W1[k * 64 + nt * 16 + l15]);
      }
      w1f[kh][nt] = f;
    }
  }
  float b1v[4], w2v[4];
#pragma unroll
  for (int nt = 0; nt < 4; ++nt) {
    b1v[nt] = b1[nt * 16 + l15];
    w2v[nt] = w2[nt * 16 + l15];
  }

  for (int it = 0; it < TILES_PER_BLOCK; ++it) {
    const int tile = blockIdx.x * TILES_PER_BLOCK + it;
    const int pairBase = tile * PAIRS;

    // ---- stage: wave w stages its 32 rows (r=w), fp32, swizzled ----
    // global rows for fixed r are 256B-contiguous: offset = bh_g*64 floats
    {
      const float* src = h + (size_t)w * RSTRIDE + (size_t)pairBase * 64;
#pragma unroll
      for (int i = 0; i < 8; ++i) {
        const int row = i * 4 + lhi;          // 0..31 within wave block
        const int ldsrow = w * 32 + row;
        f32x4 v = *(const f32x4*)(src + row * 64 + l15 * 4);  // coalesced 1KB
        const int colb = (l15 * 16) ^ ((ldsrow & 7) << 5);    // T2 swizzle
        *(f32x4*)((char*)(Tlds + ldsrow * 64) + colb) = v;
      }
    }
    // Same-wave LDS RAW: compiler inserts lgkmcnt; no barrier needed here
    // (A-fragments below read only this wave's own rows).

    // ---- MFMA: z[m][n] = sum_d T[m][d] * W1[d][n], m = wave's 32 rows ----
    f32x4 acc[2][4];
#pragma unroll
    for (int mt = 0; mt < 2; ++mt)
#pragma unroll
      for (int nt = 0; nt < 4; ++nt) acc[mt][nt] = (f32x4){0.f, 0.f, 0.f, 0.f};

#pragma unroll
    for (int mt = 0; mt < 2; ++mt) {
      const int row = w * 32 + mt * 16 + l15;      // A row = lane&15
      const char* rbase = (const char*)(Tlds + row * 64);
      const int sw = (row & 7) << 5;
#pragma unroll
      for (int kh = 0; kh < 2; ++kh) {
        const int colb = (kh * 128 + lhi * 32) ^ sw;  // 8 fp32 = 32B
        f32x4 a0 = *(const f32x4*)(rbase + colb);     // swizzle keeps +16 adjacent
        f32x4 a1 = *(const f32x4*)(rbase + colb + 16);
        bf16x8 af;
        af[0] = (short)f2bf(a0[0]); af[1] = (short)f2bf(a0[1]);
        af[2] = (short)f2bf(a0[2]); af[3] = (short)f2bf(a0[3]);
        af[4] = (short)f2bf(a1[0]); af[5] = (short)f2bf(a1[1]);
        af[6] = (short)f2bf(a1[2]); af[7] = (short)f2bf(a1[3]);
#pragma unroll
        for (int nt = 0; nt < 4; ++nt)
          acc[mt][nt] = __builtin_amdgcn_mfma_f32_16x16x32_bf16(
              af, w1f[kh][nt], acc[mt][nt], 0, 0, 0);
      }
    }

    // ---- scores: s[m] = sum_n tanh(z + b1[n]) * w2[n] ----
    // C/D layout (HW-verified): col = lane&15 (+16*nt), row = (lane>>4)*4 + j
#pragma unroll
    for (int mt = 0; mt < 2; ++mt) {
#pragma unroll
      for (int j = 0; j < 4; ++j) {
        float s = 0.f;
#pragma unroll
        for (int nt = 0; nt < 4; ++nt)
          s = fmaf(fast_tanh(acc[mt][nt][j] + b1v[nt]), w2v[nt], s);
        // reduce over the 16 columns held across lanes 0..15 of each group
        s += __shfl_xor(s, 1);
        s += __shfl_xor(s, 2);
        s += __shfl_xor(s, 4);
        s += __shfl_xor(s, 8);
        if (l15 == 0) Sc[w * 32 + mt * 16 + lhi * 4 + j] = s;
      }
    }
    __syncthreads();  // scores + all waves' T rows now visible

    // ---- softmax over r + weighted sum; wave w emits bhl in [w*8, w*8+8) ----
#pragma unroll
    for (int p = 0; p < 2; ++p) {
      const int bhl = w * 8 + p * 4 + lhi;
      const float s0 = Sc[bhl], s1 = Sc[32 + bhl];
      const float s2 = Sc[64 + bhl], s3 = Sc[96 + bhl];
      const float mx = fmaxf(fmaxf(s0, s1), fmaxf(s2, s3));
      const float e0 = __expf(s0 - mx), e1 = __expf(s1 - mx);
      const float e2 = __expf(s2 - mx), e3 = __expf(s3 - mx);
      const float inv = __builtin_amdgcn_rcpf(e0 + e1 + e2 + e3);
      const float al[4] = {e0 * inv, e1 * inv, e2 * inv, e3 * inv};
      f32x4 o = (f32x4){0.f, 0.f, 0.f, 0.f};
#pragma unroll
      for (int r = 0; r < 4; ++r) {
        const int row = r * 32 + bhl;
        const int colb = (l15 * 16) ^ ((row & 7) << 5);
        f32x4 t = *(const f32x4*)((const char*)(Tlds + row * 64) + colb);
        o += al[r] * t;  // fp32 T from LDS -> full-precision weighted sum
      }
      // lanes 0..15 cover 16 consecutive float4 of one row: 1KB coalesced store
      *(f32x4*)(out + (size_t)(pairBase + bhl) * 64 + l15 * 4) = o;
    }
    __syncthreads();  // protect Tlds/Sc before next iteration's staging
  }
}

extern "C" void kernel_launch(void* const* d_in, const int* in_sizes, int n_in,
                              void* d_out, int out_size, void* d_ws, size_t ws_size,
                              hipStream_t stream) {
  const float* h  = (const float*)d_in[0];
  const float* W1 = (const float*)d_in[1];
  const float* b1 = (const float*)d_in[2];
  const float* w2 = (const float*)d_in[3];
  // d_in[4] = b2: uniform shift across relations -> softmax-invariant, unused
  float* out = (float*)d_out;
  (void)in_sizes; (void)n_in; (void)out_size; (void)d_ws; (void)ws_size;
  hipLaunchKernelGGL(fused_relattn, dim3(NBLOCKS), dim3(256), 0, stream,
                     h, W1, b1, w2, out);
}